// Round 1
// baseline (524.664 us; speedup 1.0000x reference)
//
#include <hip/hip_runtime.h>
#include <math.h>

#define B_SZ 16384
#define NQ 10
#define DEPTH 6
#define TWO_PI_F 6.28318530717958647692f

// ---- monotone float<->uint key for atomicMax over signed floats ----
__device__ __forceinline__ unsigned fkey(float x){
  unsigned b = __float_as_uint(x);
  return (b & 0x80000000u) ? ~b : (b | 0x80000000u);
}
__device__ __forceinline__ float funkey(unsigned k){
  unsigned b = (k & 0x80000000u) ? (k ^ 0x80000000u) : ~k;
  return __uint_as_float(b);
}

__global__ void k0_init(unsigned* gkey){ *gkey = 0u; }

// ---- K1: 6x6 avg-pool of 24x24 crop -> 16 feats -> encoder matvec -> global max ----
__global__ __launch_bounds__(256) void k1_encode(const float* __restrict__ x,
    const float* __restrict__ encW, const float* __restrict__ encB,
    float* __restrict__ encOut, unsigned* __restrict__ gkey)
{
  int s = blockIdx.x * 256 + threadIdx.x;
  const float* xs = x + (size_t)s * 784;
  float pool[16];
  #pragma unroll
  for (int i = 0; i < 16; ++i) pool[i] = 0.f;
  #pragma unroll
  for (int row = 0; row < 24; ++row){
    int p = row / 6;
    #pragma unroll
    for (int c4 = 0; c4 < 6; ++c4){
      float4 v = *reinterpret_cast<const float4*>(xs + row * 28 + c4 * 4);
      int c0 = c4 * 4;
      pool[p*4 + (c0+0)/6] += v.x;
      pool[p*4 + (c0+1)/6] += v.y;
      pool[p*4 + (c0+2)/6] += v.z;
      pool[p*4 + (c0+3)/6] += v.w;
    }
  }
  #pragma unroll
  for (int i = 0; i < 16; ++i) pool[i] *= (1.f/36.f);

  float m = -INFINITY;
  #pragma unroll
  for (int i = 0; i < NQ; ++i){
    float e = encB[i];
    #pragma unroll
    for (int k = 0; k < 16; ++k) e = fmaf(pool[k], encW[i*16+k], e);
    encOut[(size_t)s*NQ + i] = e;
    m = fmaxf(m, e);
  }
  // wave max reduce
  #pragma unroll
  for (int st = 1; st < 64; st <<= 1) m = fmaxf(m, __shfl_xor(m, st, 64));
  __shared__ float wm[4];
  int lane = threadIdx.x & 63, w = threadIdx.x >> 6;
  if (lane == 0) wm[w] = m;
  __syncthreads();
  if (threadIdx.x == 0){
    float mm = fmaxf(fmaxf(wm[0], wm[1]), fmaxf(wm[2], wm[3]));
    atomicMax(gkey, fkey(mm));
  }
}

// ---- K2: one wave per sample; 1024 amps in registers (16 complex/lane) ----
// amp index b: bits[3:0]=register (qubits 0..3), bits[9:4]=lane (qubits 4..9)
__global__ __launch_bounds__(256) void k2_qsim(
    const float* __restrict__ enc, const unsigned* __restrict__ gkey,
    const float* __restrict__ wts, const float* __restrict__ fcW,
    const float* __restrict__ fcB, float* __restrict__ outB)
{
  __shared__ float G[DEPTH*NQ*8]; // u00r,u00i,u01r,u01i,u10r,u10i,u11r,u11i
  int tid = threadIdx.x;
  if (tid < DEPTH*NQ){
    float ax = wts[tid*2+0] * 0.5f;
    float az = wts[tid*2+1] * 0.5f;
    float ca = cosf(ax), sa = sinf(ax), cz = cosf(az), sz = sinf(az);
    float* g = &G[tid*8];
    g[0] =  ca*cz; g[1] = -ca*sz;   // u00 = ca*e^{-i az}
    g[2] = -sa*sz; g[3] = -sa*cz;   // u01 = -i*sa*e^{-i az}
    g[4] =  sa*sz; g[5] = -sa*cz;   // u10 = -i*sa*e^{+i az}
    g[6] =  ca*cz; g[7] =  ca*sz;   // u11 = ca*e^{+i az}
  }
  __syncthreads();

  int lane = tid & 63;
  int s = blockIdx.x * 4 + (tid >> 6);
  float scale = TWO_PI_F / (funkey(*gkey) + 1e-8f);

  float cc[NQ], sn[NQ];
  #pragma unroll
  for (int i = 0; i < NQ; ++i){
    float half = enc[(size_t)s*NQ + i] * scale * 0.5f;
    cc[i] = cosf(half); sn[i] = sinf(half);
  }
  // initial product state (all-real): RY encoding fused
  float la = 1.f;
  #pragma unroll
  for (int j = 0; j < 6; ++j) la *= ((lane>>j)&1) ? sn[4+j] : cc[4+j];
  float re[16], im[16];
  #pragma unroll
  for (int r = 0; r < 16; ++r){
    float v = la;
    v *= (r&1) ? sn[0] : cc[0];
    v *= (r&2) ? sn[1] : cc[1];
    v *= (r&4) ? sn[2] : cc[2];
    v *= (r&8) ? sn[3] : cc[3];
    re[r] = v; im[r] = 0.f;
  }

  #pragma unroll 1
  for (int d = 0; d < DEPTH; ++d){
    const float* Gd = &G[d*NQ*8];
    // qubits 0..3: register-bit gates
    #pragma unroll
    for (int q = 0; q < 4; ++q){
      float u00r=Gd[q*8+0], u00i=Gd[q*8+1], u01r=Gd[q*8+2], u01i=Gd[q*8+3];
      float u10r=Gd[q*8+4], u10i=Gd[q*8+5], u11r=Gd[q*8+6], u11i=Gd[q*8+7];
      #pragma unroll
      for (int r = 0; r < 16; ++r) if (!(r & (1<<q))){
        int r2 = r | (1<<q);
        float ar=re[r], ai=im[r], br=re[r2], bi=im[r2];
        re[r]  = u00r*ar - u00i*ai + u01r*br - u01i*bi;
        im[r]  = u00r*ai + u00i*ar + u01r*bi + u01i*br;
        re[r2] = u10r*ar - u10i*ai + u11r*br - u11i*bi;
        im[r2] = u10r*ai + u10i*ar + u11r*bi + u11i*br;
      }
    }
    // qubits 4..9: lane-bit gates via shfl_xor
    #pragma unroll
    for (int q = 4; q < 10; ++q){
      const int j = q - 4, mask = 1 << j;
      float u00r=Gd[q*8+0], u00i=Gd[q*8+1], u01r=Gd[q*8+2], u01i=Gd[q*8+3];
      float u10r=Gd[q*8+4], u10i=Gd[q*8+5], u11r=Gd[q*8+6], u11i=Gd[q*8+7];
      bool hi = (lane >> j) & 1;
      float cAr = hi ? u11r : u00r, cAi = hi ? u11i : u00i;
      float cPr = hi ? u10r : u01r, cPi = hi ? u10i : u01i;
      #pragma unroll
      for (int r = 0; r < 16; ++r){
        float pr = __shfl_xor(re[r], mask, 64);
        float pi = __shfl_xor(im[r], mask, 64);
        float ar = re[r], ai = im[r];
        re[r] = cAr*ar - cAi*ai + cPr*pr - cPi*pi;
        im[r] = cAr*ai + cAi*ar + cPr*pi + cPi*pr;
      }
    }
    // CNOT ring
    // (0,1),(1,2),(2,3): reg-reg, static swaps
    #pragma unroll
    for (int cq = 0; cq < 3; ++cq){
      const int tq = cq + 1;
      #pragma unroll
      for (int r = 0; r < 16; ++r) if (((r>>cq)&1) && !((r>>tq)&1)){
        int r2 = r ^ (1<<tq);
        float t = re[r]; re[r] = re[r2]; re[r2] = t;
        t = im[r]; im[r] = im[r2]; im[r2] = t;
      }
    }
    // (3,4): ctl = reg bit3, tgt = lane bit0
    #pragma unroll
    for (int r = 8; r < 16; ++r){
      re[r] = __shfl_xor(re[r], 1, 64);
      im[r] = __shfl_xor(im[r], 1, 64);
    }
    // (4,5)..(8,9): lane-lane
    #pragma unroll
    for (int cq = 4; cq < 9; ++cq){
      const int jc = cq - 4, mt = 1 << (cq - 3);
      bool ctl = (lane >> jc) & 1;
      #pragma unroll
      for (int r = 0; r < 16; ++r){
        float tr = __shfl_xor(re[r], mt, 64);
        float ti = __shfl_xor(im[r], mt, 64);
        re[r] = ctl ? tr : re[r];
        im[r] = ctl ? ti : im[r];
      }
    }
    // (9,0): ctl = lane bit5, tgt = reg bit0
    {
      bool ctl = (lane >> 5) & 1;
      #pragma unroll
      for (int r = 0; r < 16; r += 2){
        float a = re[r], b = re[r+1];
        re[r] = ctl ? b : a; re[r+1] = ctl ? a : b;
        a = im[r]; b = im[r+1];
        im[r] = ctl ? b : a; im[r+1] = ctl ? a : b;
      }
    }
  }

  // measurement: z_i = P(bit_i=0) - P(bit_i=1)
  float p[16];
  #pragma unroll
  for (int r = 0; r < 16; ++r) p[r] = re[r]*re[r] + im[r]*im[r];
  float z[NQ];
  #pragma unroll
  for (int q = 0; q < 4; ++q){
    float t = 0.f;
    #pragma unroll
    for (int r = 0; r < 16; ++r) t += ((r>>q)&1) ? -p[r] : p[r];
    #pragma unroll
    for (int st = 1; st < 64; st <<= 1) t += __shfl_xor(t, st, 64);
    z[q] = t;
  }
  float S = 0.f;
  #pragma unroll
  for (int r = 0; r < 16; ++r) S += p[r];
  #pragma unroll
  for (int j = 0; j < 6; ++j){
    float t = ((lane>>j)&1) ? -S : S;
    #pragma unroll
    for (int st = 1; st < 64; st <<= 1) t += __shfl_xor(t, st, 64);
    z[4+j] = t;
  }

  // fused FC: out[o] = fc_b[o] + sum_i z_i * fc_W[o,i]
  int o = lane & 3;
  float acc = fcB[o];
  #pragma unroll
  for (int i = 0; i < NQ; ++i) acc = fmaf(z[i], fcW[o*NQ+i], acc);
  if (lane < 4) outB[(size_t)s*4 + o] = acc;
}

// ---- K3: deterministic BN stats (single block) ----
__global__ __launch_bounds__(1024) void k3_stats(const float* __restrict__ outB,
                                                 float* __restrict__ stats)
{
  int tid = threadIdx.x;
  float sum[4] = {0,0,0,0}, sq[4] = {0,0,0,0};
  for (int row = tid; row < B_SZ; row += 1024){
    float4 v = *reinterpret_cast<const float4*>(outB + (size_t)row*4);
    sum[0]+=v.x; sq[0]+=v.x*v.x;
    sum[1]+=v.y; sq[1]+=v.y*v.y;
    sum[2]+=v.z; sq[2]+=v.z*v.z;
    sum[3]+=v.w; sq[3]+=v.w*v.w;
  }
  #pragma unroll
  for (int k = 0; k < 4; ++k){
    #pragma unroll
    for (int st = 1; st < 64; st <<= 1){
      sum[k] += __shfl_xor(sum[k], st, 64);
      sq[k]  += __shfl_xor(sq[k],  st, 64);
    }
  }
  __shared__ float ls[16][8];
  int lane = tid & 63, w = tid >> 6;
  if (lane == 0){
    #pragma unroll
    for (int k = 0; k < 4; ++k){ ls[w][k] = sum[k]; ls[w][4+k] = sq[k]; }
  }
  __syncthreads();
  if (tid == 0){
    float fs[8];
    #pragma unroll
    for (int k = 0; k < 8; ++k){
      float a = 0.f;
      for (int w2 = 0; w2 < 16; ++w2) a += ls[w2][k];
      fs[k] = a;
    }
    #pragma unroll
    for (int k = 0; k < 4; ++k){
      float mean = fs[k] * (1.f/B_SZ);
      float var  = fs[4+k] * (1.f/B_SZ) - mean*mean;
      stats[k]   = mean;
      stats[4+k] = rsqrtf(var + 1e-5f);
    }
  }
}

// ---- K4: apply BN ----
__global__ __launch_bounds__(256) void k4_bn(const float* __restrict__ outB,
    const float* __restrict__ stats, const float* __restrict__ gamma,
    const float* __restrict__ beta, float* __restrict__ out)
{
  int idx = blockIdx.x * 256 + threadIdx.x;
  int c = idx & 3;
  float v = outB[idx];
  out[idx] = gamma[c] * (v - stats[c]) * stats[4+c] + beta[c];
}

extern "C" void kernel_launch(void* const* d_in, const int* in_sizes, int n_in,
                              void* d_out, int out_size, void* d_ws, size_t ws_size,
                              hipStream_t stream)
{
  const float* x     = (const float*)d_in[0];
  const float* encW  = (const float*)d_in[1];
  const float* encB  = (const float*)d_in[2];
  const float* wts   = (const float*)d_in[3];
  const float* fcW   = (const float*)d_in[4];
  const float* fcB   = (const float*)d_in[5];
  const float* gamma = (const float*)d_in[6];
  const float* beta  = (const float*)d_in[7];

  char* ws = (char*)d_ws;
  unsigned* gkey = (unsigned*)ws;
  float* enc   = (float*)(ws + 256);
  float* outB  = (float*)(ws + 256 + (size_t)B_SZ*NQ*4);
  float* stats = (float*)(ws + 256 + (size_t)B_SZ*NQ*4 + (size_t)B_SZ*4*4);

  hipLaunchKernelGGL(k0_init, dim3(1), dim3(1), 0, stream, gkey);
  hipLaunchKernelGGL(k1_encode, dim3(B_SZ/256), dim3(256), 0, stream,
                     x, encW, encB, enc, gkey);
  hipLaunchKernelGGL(k2_qsim, dim3(B_SZ/4), dim3(256), 0, stream,
                     enc, gkey, wts, fcW, fcB, outB);
  hipLaunchKernelGGL(k3_stats, dim3(1), dim3(1024), 0, stream, outB, stats);
  hipLaunchKernelGGL(k4_bn, dim3(B_SZ*4/256), dim3(256), 0, stream,
                     outB, stats, gamma, beta, (float*)d_out);
}

// Round 2
// 410.827 us; speedup vs baseline: 1.2771x; 1.2771x over previous
//
#include <hip/hip_runtime.h>
#include <math.h>

#define B_SZ 16384
#define NQ 10
#define DEPTH 6
#define NGATES (DEPTH*NQ)

// ---- constexpr GF(2) tracking of the CNOT ring ----
// S_log[l] = S_phys[P(l)].  CNOT(c,t): P' = P∘T, T(e_c)=e_c^e_t.
// cols[q] = P(e_q) = phys xor-mask for a gate on logical qubit q.
// rows[q] = row q of P^{-1}: logical bit q of phys p = parity(rows[q] & p).
struct Tables {
  int m[DEPTH][NQ];
  int R[DEPTH][NQ];
  int meas[NQ];
};
constexpr Tables make_tables(){
  Tables t{};
  int cols[NQ] = {}, rows[NQ] = {};
  for (int i = 0; i < NQ; ++i){ cols[i] = 1 << i; rows[i] = 1 << i; }
  for (int d = 0; d < DEPTH; ++d){
    for (int q = 0; q < NQ; ++q){ t.m[d][q] = cols[q]; t.R[d][q] = rows[q]; }
    for (int c = 0; c < NQ; ++c){          // ring: (0,1)..(8,9),(9,0)
      int tt = (c + 1) % NQ;
      cols[c]  ^= cols[tt];
      rows[tt] ^= rows[c];
    }
  }
  for (int q = 0; q < NQ; ++q) t.meas[q] = rows[q];
  return t;
}
constexpr Tables TAB = make_tables();

// ---- monotone float<->uint key for atomicMax over signed floats ----
__device__ __forceinline__ unsigned fkey(float x){
  unsigned b = __float_as_uint(x);
  return (b & 0x80000000u) ? ~b : (b | 0x80000000u);
}
__device__ __forceinline__ float funkey(unsigned k){
  unsigned b = (k & 0x80000000u) ? (k ^ 0x80000000u) : ~k;
  return __uint_as_float(b);
}

// lane-xor exchange: DPP quad_perm for masks 1..3 (VALU pipe), shfl otherwise
template<int LM>
__device__ __forceinline__ float lanexor(float x){
  if constexpr (LM == 1 || LM == 2 || LM == 3){
    constexpr int ctrl = (0^LM) | ((1^LM)<<2) | ((2^LM)<<4) | ((3^LM)<<6);
    return __uint_as_float((unsigned)__builtin_amdgcn_update_dpp(
        0, (int)__float_as_uint(x), ctrl, 0xF, 0xF, true));
  } else {
    return __shfl_xor(x, LM, 64);
  }
}

// ---- prep: gate coefficients (wave-uniform) + gkey reset ----
// per gate store (u00r, u00i, u10r, u10i); u11=conj(u00), u01=-conj(u10)
__global__ void k_prep(const float* __restrict__ wts, float4* __restrict__ gc,
                       unsigned* __restrict__ gkey){
  int g = threadIdx.x;
  if (g < NGATES){
    float ax = wts[g*2+0] * 0.5f, az = wts[g*2+1] * 0.5f;
    float ca = cosf(ax), sa = sinf(ax), cz = cosf(az), sz = sinf(az);
    gc[g] = make_float4(ca*cz, -ca*sz, sa*sz, -sa*cz);
  }
  if (g == NGATES) *gkey = 0u;
}

// ---- K1: pool -> encode -> global max ----
__global__ __launch_bounds__(256) void k1_encode(const float* __restrict__ x,
    const float* __restrict__ encW, const float* __restrict__ encB,
    float* __restrict__ encOut, unsigned* __restrict__ gkey)
{
  int s = blockIdx.x * 256 + threadIdx.x;
  const float* xs = x + (size_t)s * 784;
  float pool[16];
  #pragma unroll
  for (int i = 0; i < 16; ++i) pool[i] = 0.f;
  #pragma unroll
  for (int row = 0; row < 24; ++row){
    int p = row / 6;
    #pragma unroll
    for (int c4 = 0; c4 < 6; ++c4){
      float4 v = *reinterpret_cast<const float4*>(xs + row * 28 + c4 * 4);
      int c0 = c4 * 4;
      pool[p*4 + (c0+0)/6] += v.x;
      pool[p*4 + (c0+1)/6] += v.y;
      pool[p*4 + (c0+2)/6] += v.z;
      pool[p*4 + (c0+3)/6] += v.w;
    }
  }
  #pragma unroll
  for (int i = 0; i < 16; ++i) pool[i] *= (1.f/36.f);

  float m = -INFINITY;
  #pragma unroll
  for (int i = 0; i < NQ; ++i){
    float e = encB[i];
    #pragma unroll
    for (int k = 0; k < 16; ++k) e = fmaf(pool[k], encW[i*16+k], e);
    encOut[(size_t)s*NQ + i] = e;
    m = fmaxf(m, e);
  }
  #pragma unroll
  for (int st = 1; st < 64; st <<= 1) m = fmaxf(m, __shfl_xor(m, st, 64));
  __shared__ float wm[4];
  int lane = threadIdx.x & 63, w = threadIdx.x >> 6;
  if (lane == 0) wm[w] = m;
  __syncthreads();
  if (threadIdx.x == 0){
    float mm = fmaxf(fmaxf(wm[0], wm[1]), fmaxf(wm[2], wm[3]));
    atomicMax(gkey, fkey(mm));
  }
}

// ---- gate application, fully specialized via constexpr masks ----
template<int G>
__device__ __forceinline__ void run_gates(float (&re)[16], float (&im)[16],
    const float4* __restrict__ gc, int lane)
{
  if constexpr (G < NGATES){
    constexpr int d  = G / NQ, q = G % NQ;
    constexpr int m  = TAB.m[d][q];
    constexpr int R  = TAB.R[d][q];
    constexpr int rm = m & 15;
    constexpr int lm = m >> 4;
    constexpr int Rl = R >> 4;
    constexpr int Rr = R & 15;

    float4 c = gc[G];                       // uniform -> s_load
    unsigned sgn = 0;
    if constexpr (Rl != 0) sgn = (unsigned)(__popc(Rl & lane) << 31);
    float u00i_s = __uint_as_float(__float_as_uint(c.y) ^ sgn);
    float u10r_s = __uint_as_float(__float_as_uint(c.z) ^ sgn ^ 0x80000000u);

    float nre[16], nim[16];
    #pragma unroll
    for (int r = 0; r < 16; ++r){
      float ar = re[r], ai = im[r];
      float br, bi;
      if constexpr (lm != 0){
        br = lanexor<lm>(re[r ^ rm]);
        bi = lanexor<lm>(im[r ^ rm]);
      } else {
        br = re[r ^ rm]; bi = im[r ^ rm];
      }
      if ((__builtin_popcount(r & Rr) & 1) == 0){
        nre[r] = c.x*ar - u00i_s*ai + u10r_s*br - c.w*bi;
        nim[r] = c.x*ai + u00i_s*ar + u10r_s*bi + c.w*br;
      } else {
        nre[r] = c.x*ar + u00i_s*ai - u10r_s*br - c.w*bi;
        nim[r] = c.x*ai - u00i_s*ar - u10r_s*bi + c.w*br;
      }
    }
    #pragma unroll
    for (int r = 0; r < 16; ++r){ re[r] = nre[r]; im[r] = nim[r]; }
    run_gates<G+1>(re, im, gc, lane);
  }
}

// ---- K2: one wave per sample, state fully in registers ----
// amp index: bits[3:0] = register, bits[9:4] = lane
__global__ __launch_bounds__(256) void k2_qsim(
    const float* __restrict__ enc, const unsigned* __restrict__ gkey,
    const float4* __restrict__ gc, const float* __restrict__ fcW,
    const float* __restrict__ fcB, float* __restrict__ outB)
{
  int tid  = threadIdx.x;
  int lane = tid & 63;
  int s    = blockIdx.x * 4 + (tid >> 6);

  float invr = 3.14159265358979f / (funkey(*gkey) + 1e-8f); // half-angle scale
  float cc[NQ], sn[NQ];
  #pragma unroll
  for (int i = 0; i < NQ; ++i){
    float ang = enc[(size_t)s*NQ + i] * invr;
    cc[i] = __cosf(ang); sn[i] = __sinf(ang);
  }
  float la = 1.f;
  #pragma unroll
  for (int j = 0; j < 6; ++j) la *= ((lane>>j)&1) ? sn[4+j] : cc[4+j];
  float re[16], im[16];
  #pragma unroll
  for (int r = 0; r < 16; ++r){
    float v = la;
    v *= (r&1) ? sn[0] : cc[0];
    v *= (r&2) ? sn[1] : cc[1];
    v *= (r&4) ? sn[2] : cc[2];
    v *= (r&8) ? sn[3] : cc[3];
    re[r] = v; im[r] = 0.f;
  }

  run_gates<0>(re, im, gc, lane);

  // measurement fused into FC: o[j] = sum_q fcW[j,q] * z_q
  float p[16];
  #pragma unroll
  for (int r = 0; r < 16; ++r) p[r] = re[r]*re[r] + im[r]*im[r];
  float o[4] = {0.f, 0.f, 0.f, 0.f};
  #pragma unroll
  for (int q = 0; q < NQ; ++q){
    int R = TAB.meas[q];
    float tq = 0.f;
    #pragma unroll
    for (int r = 0; r < 16; ++r){
      if ((__builtin_popcount(r & (R & 15)) & 1) == 0) tq += p[r]; else tq -= p[r];
    }
    unsigned sg = (unsigned)(__popc((R >> 4) & lane) << 31);
    tq = __uint_as_float(__float_as_uint(tq) ^ sg);
    #pragma unroll
    for (int j = 0; j < 4; ++j) o[j] = fmaf(tq, fcW[j*NQ + q], o[j]);
  }
  #pragma unroll
  for (int j = 0; j < 4; ++j){
    #pragma unroll
    for (int st = 1; st < 64; st <<= 1) o[j] += __shfl_xor(o[j], st, 64);
  }
  if (lane == 0){
    float4 out4 = make_float4(o[0]+fcB[0], o[1]+fcB[1], o[2]+fcB[2], o[3]+fcB[3]);
    *reinterpret_cast<float4*>(&outB[(size_t)s*4]) = out4;
  }
}

// ---- K3: deterministic BN stats (single block) ----
__global__ __launch_bounds__(1024) void k3_stats(const float* __restrict__ outB,
                                                 float* __restrict__ stats)
{
  int tid = threadIdx.x;
  float sum[4] = {0,0,0,0}, sq[4] = {0,0,0,0};
  for (int row = tid; row < B_SZ; row += 1024){
    float4 v = *reinterpret_cast<const float4*>(outB + (size_t)row*4);
    sum[0]+=v.x; sq[0]+=v.x*v.x;
    sum[1]+=v.y; sq[1]+=v.y*v.y;
    sum[2]+=v.z; sq[2]+=v.z*v.z;
    sum[3]+=v.w; sq[3]+=v.w*v.w;
  }
  #pragma unroll
  for (int k = 0; k < 4; ++k){
    #pragma unroll
    for (int st = 1; st < 64; st <<= 1){
      sum[k] += __shfl_xor(sum[k], st, 64);
      sq[k]  += __shfl_xor(sq[k],  st, 64);
    }
  }
  __shared__ float ls[16][8];
  int lane = tid & 63, w = tid >> 6;
  if (lane == 0){
    #pragma unroll
    for (int k = 0; k < 4; ++k){ ls[w][k] = sum[k]; ls[w][4+k] = sq[k]; }
  }
  __syncthreads();
  if (tid == 0){
    float fs[8];
    #pragma unroll
    for (int k = 0; k < 8; ++k){
      float a = 0.f;
      for (int w2 = 0; w2 < 16; ++w2) a += ls[w2][k];
      fs[k] = a;
    }
    #pragma unroll
    for (int k = 0; k < 4; ++k){
      float mean = fs[k] * (1.f/B_SZ);
      float var  = fs[4+k] * (1.f/B_SZ) - mean*mean;
      stats[k]   = mean;
      stats[4+k] = rsqrtf(var + 1e-5f);
    }
  }
}

// ---- K4: apply BN ----
__global__ __launch_bounds__(256) void k4_bn(const float* __restrict__ outB,
    const float* __restrict__ stats, const float* __restrict__ gamma,
    const float* __restrict__ beta, float* __restrict__ out)
{
  int idx = blockIdx.x * 256 + threadIdx.x;
  int c = idx & 3;
  float v = outB[idx];
  out[idx] = gamma[c] * (v - stats[c]) * stats[4+c] + beta[c];
}

extern "C" void kernel_launch(void* const* d_in, const int* in_sizes, int n_in,
                              void* d_out, int out_size, void* d_ws, size_t ws_size,
                              hipStream_t stream)
{
  const float* x     = (const float*)d_in[0];
  const float* encW  = (const float*)d_in[1];
  const float* encB  = (const float*)d_in[2];
  const float* wts   = (const float*)d_in[3];
  const float* fcW   = (const float*)d_in[4];
  const float* fcB   = (const float*)d_in[5];
  const float* gamma = (const float*)d_in[6];
  const float* beta  = (const float*)d_in[7];

  char* ws = (char*)d_ws;
  unsigned* gkey = (unsigned*)ws;                       // 4 B
  float4*  gc    = (float4*)(ws + 256);                 // 960 B
  float*   enc   = (float*)(ws + 4096);                 // 16384*10*4
  float*   outB  = (float*)(ws + 4096 + (size_t)B_SZ*NQ*4);
  float*   stats = (float*)(ws + 4096 + (size_t)B_SZ*NQ*4 + (size_t)B_SZ*4*4);

  hipLaunchKernelGGL(k_prep, dim3(1), dim3(64), 0, stream, wts, gc, gkey);
  hipLaunchKernelGGL(k1_encode, dim3(B_SZ/256), dim3(256), 0, stream,
                     x, encW, encB, enc, gkey);
  hipLaunchKernelGGL(k2_qsim, dim3(B_SZ/4), dim3(256), 0, stream,
                     enc, gkey, gc, fcW, fcB, outB);
  hipLaunchKernelGGL(k3_stats, dim3(1), dim3(1024), 0, stream, outB, stats);
  hipLaunchKernelGGL(k4_bn, dim3(B_SZ*4/256), dim3(256), 0, stream,
                     outB, stats, gamma, beta, (float*)d_out);
}

// Round 3
// 246.507 us; speedup vs baseline: 2.1284x; 1.6666x over previous
//
#include <hip/hip_runtime.h>
#include <math.h>

#define B_SZ 16384
#define NQ 10
#define DEPTH 6

// ---- constexpr GF(2) tracking of the CNOT ring ----
struct Tables {
  int m[DEPTH][NQ];   // phys xor-mask for gate on logical q at layer d
  int R[DEPTH][NQ];   // logical bit q of phys p = parity(R & p)
  int meas[NQ];       // final-basis rows for measurement
};
constexpr Tables make_tables(){
  Tables t{};
  int cols[NQ] = {}, rows[NQ] = {};
  for (int i = 0; i < NQ; ++i){ cols[i] = 1 << i; rows[i] = 1 << i; }
  for (int d = 0; d < DEPTH; ++d){
    for (int q = 0; q < NQ; ++q){ t.m[d][q] = cols[q]; t.R[d][q] = rows[q]; }
    for (int c = 0; c < NQ; ++c){          // ring: (0,1)..(8,9),(9,0)
      int tt = (c + 1) % NQ;
      cols[c]  ^= cols[tt];
      rows[tt] ^= rows[c];
    }
  }
  for (int q = 0; q < NQ; ++q) t.meas[q] = rows[q];
  return t;
}
constexpr Tables TAB = make_tables();

// ---- monotone float<->uint key for atomicMax over signed floats ----
__device__ __forceinline__ unsigned fkey(float x){
  unsigned b = __float_as_uint(x);
  return (b & 0x80000000u) ? ~b : (b | 0x80000000u);
}
__device__ __forceinline__ float funkey(unsigned k){
  unsigned b = (k & 0x80000000u) ? (k ^ 0x80000000u) : ~k;
  return __uint_as_float(b);
}

// lane-xor exchange: DPP quad_perm for masks 1..3 (VALU pipe), shfl otherwise
template<int LM>
__device__ __forceinline__ float lanexor(float x){
  if constexpr (LM == 1 || LM == 2 || LM == 3){
    constexpr int ctrl = (0^LM) | ((1^LM)<<2) | ((2^LM)<<4) | ((3^LM)<<6);
    return __uint_as_float((unsigned)__builtin_amdgcn_update_dpp(
        0, (int)__float_as_uint(x), ctrl, 0xF, 0xF, true));
  } else {
    return __shfl_xor(x, LM, 64);
  }
}

// ---- prep: layer-0 fused 1q unitaries, Rx coeffs, diagonal phase tables ----
__global__ __launch_bounds__(256) void k_prep(const float* __restrict__ wts,
    float4* __restrict__ U0,     // 20: q*2+{0:(u00,u01),1:(u10,u11)}
    float2* __restrict__ gc2,    // 50: (d-1)*10+q -> (cos ax, sin ax)
    float2* __restrict__ phase,  // 4*1024: layers 1..4 diagonal
    unsigned* __restrict__ gkey)
{
  int idx = blockIdx.x * 256 + threadIdx.x;
  if (idx < 4096){
    int layer = 1 + (idx >> 10);
    int p = idx & 1023;
    float phi = 0.f;
    for (int q = 0; q < NQ; ++q){
      float az = wts[(layer*NQ + q)*2 + 1] * 0.5f;
      phi += (__popc(TAB.R[layer][q] & p) & 1) ? az : -az;
    }
    phase[idx] = make_float2(cosf(phi), sinf(phi));
  }
  if (blockIdx.x == 0){
    int t = threadIdx.x;
    if (t < NQ){
      float ax = wts[t*2+0]*0.5f, az = wts[t*2+1]*0.5f;
      float ca=cosf(ax), sa=sinf(ax), cz=cosf(az), sz=sinf(az);
      U0[t*2+0] = make_float4(ca*cz, -ca*sz, -sa*sz, -sa*cz); // u00r,u00i,u01r,u01i
      U0[t*2+1] = make_float4(sa*sz, -sa*cz,  ca*cz,  ca*sz); // u10r,u10i,u11r,u11i
    } else if (t >= 64 && t < 64 + 50){
      int g = t - 64;                     // (d-1)*10+q, d=1..5
      int d = 1 + g/10, q = g - (d-1)*10;
      float ax = wts[(d*NQ+q)*2+0]*0.5f;
      gc2[g] = make_float2(cosf(ax), sinf(ax));
    } else if (t == 120){
      *gkey = 0u;
    }
  }
}

// ---- K1: pool -> encode -> global max ----
__global__ __launch_bounds__(256) void k1_encode(const float* __restrict__ x,
    const float* __restrict__ encW, const float* __restrict__ encB,
    float* __restrict__ encOut, unsigned* __restrict__ gkey)
{
  int s = blockIdx.x * 256 + threadIdx.x;
  const float* xs = x + (size_t)s * 784;
  float pool[16];
  #pragma unroll
  for (int i = 0; i < 16; ++i) pool[i] = 0.f;
  #pragma unroll
  for (int row = 0; row < 24; ++row){
    int p = row / 6;
    #pragma unroll
    for (int c4 = 0; c4 < 6; ++c4){
      float4 v = *reinterpret_cast<const float4*>(xs + row * 28 + c4 * 4);
      int c0 = c4 * 4;
      pool[p*4 + (c0+0)/6] += v.x;
      pool[p*4 + (c0+1)/6] += v.y;
      pool[p*4 + (c0+2)/6] += v.z;
      pool[p*4 + (c0+3)/6] += v.w;
    }
  }
  #pragma unroll
  for (int i = 0; i < 16; ++i) pool[i] *= (1.f/36.f);

  float m = -INFINITY;
  #pragma unroll
  for (int i = 0; i < NQ; ++i){
    float e = encB[i];
    #pragma unroll
    for (int k = 0; k < 16; ++k) e = fmaf(pool[k], encW[i*16+k], e);
    encOut[(size_t)s*NQ + i] = e;
    m = fmaxf(m, e);
  }
  #pragma unroll
  for (int st = 1; st < 64; st <<= 1) m = fmaxf(m, __shfl_xor(m, st, 64));
  __shared__ float wm[4];
  int lane = threadIdx.x & 63, w = threadIdx.x >> 6;
  if (lane == 0) wm[w] = m;
  __syncthreads();
  if (threadIdx.x == 0){
    float mm = fmaxf(fmaxf(wm[0], wm[1]), fmaxf(wm[2], wm[3]));
    atomicMax(gkey, fkey(mm));
  }
}

// ---- Rx gate (no phases, no signs): 4 FMA-class ops per amp ----
template<int D, int Q>
__device__ __forceinline__ void rx_gate(float (&re)[16], float (&im)[16],
    const float2* __restrict__ gc2, int lane)
{
  constexpr int m  = TAB.m[D][Q];
  constexpr int rm = m & 15;
  constexpr int lm = m >> 4;
  float2 c = gc2[(D-1)*NQ + Q];     // wave-uniform -> s_load
  float ca = c.x, sa = c.y;

  if constexpr (lm == 0){
    constexpr int lb = rm & (-rm);  // pair-enumeration bit
    #pragma unroll
    for (int r = 0; r < 16; ++r) if (!(r & lb)){
      int r2 = r ^ rm;
      float ar = re[r],  ai = im[r];
      float br = re[r2], bi = im[r2];
      re[r]  = fmaf(sa, bi,  ca*ar);
      im[r]  = fmaf(sa, -br, ca*ai);
      re[r2] = fmaf(sa, ai,  ca*br);
      im[r2] = fmaf(sa, -ar, ca*bi);
    }
  } else {
    float nre[16], nim[16];
    #pragma unroll
    for (int r = 0; r < 16; ++r){
      float br = lanexor<lm>(re[r ^ rm]);
      float bi = lanexor<lm>(im[r ^ rm]);
      nre[r] = fmaf(sa, bi,  ca*re[r]);
      nim[r] = fmaf(sa, -br, ca*im[r]);
    }
    #pragma unroll
    for (int r = 0; r < 16; ++r){ re[r] = nre[r]; im[r] = nim[r]; }
  }
}

template<int D>
__device__ __forceinline__ void run_layer(float (&re)[16], float (&im)[16],
    const float2* __restrict__ gc2, const float4* __restrict__ phase4, int lane)
{
  float4 phv[8];
  if constexpr (D <= 4){
    const float4* __restrict__ pp = phase4 + (size_t)(D-1)*512 + lane*8;
    #pragma unroll
    for (int j = 0; j < 8; ++j) phv[j] = pp[j];   // prefetch, consumed after gates
  }
  rx_gate<D,0>(re, im, gc2, lane);
  rx_gate<D,1>(re, im, gc2, lane);
  rx_gate<D,2>(re, im, gc2, lane);
  rx_gate<D,3>(re, im, gc2, lane);
  rx_gate<D,4>(re, im, gc2, lane);
  rx_gate<D,5>(re, im, gc2, lane);
  rx_gate<D,6>(re, im, gc2, lane);
  rx_gate<D,7>(re, im, gc2, lane);
  rx_gate<D,8>(re, im, gc2, lane);
  rx_gate<D,9>(re, im, gc2, lane);
  if constexpr (D <= 4){
    #pragma unroll
    for (int r = 0; r < 16; ++r){
      float cp = (r & 1) ? phv[r>>1].z : phv[r>>1].x;
      float sp = (r & 1) ? phv[r>>1].w : phv[r>>1].y;
      float ar = re[r], ai = im[r];
      re[r] = fmaf(cp, ar, -sp*ai);
      im[r] = fmaf(cp, ai,  sp*ar);
    }
  }
  // D == 5: final diagonal dropped — phases don't affect |amp|^2
}

// ---- K2: one wave per sample, 1024 amps in registers ----
// amp index: bits[3:0] = register, bits[9:4] = lane
__global__ __launch_bounds__(256) void k2_qsim(
    const float* __restrict__ enc, const unsigned* __restrict__ gkey,
    const float4* __restrict__ U0, const float2* __restrict__ gc2,
    const float4* __restrict__ phase4,
    const float* __restrict__ fcW, const float* __restrict__ fcB,
    float* __restrict__ outB)
{
  int tid  = threadIdx.x;
  int lane = tid & 63;
  int s    = blockIdx.x * 4 + (tid >> 6);

  float invr = 3.14159265358979f / (funkey(*gkey) + 1e-8f); // half-angle scale

  // per-qubit post-layer-0 states (alpha, beta) = U0_q * (cos, sin)
  float par[NQ], pai[NQ], pbr[NQ], pbi[NQ];
  #pragma unroll
  for (int q = 0; q < NQ; ++q){
    float ang = enc[(size_t)s*NQ + q] * invr;
    float c = __cosf(ang), sv = __sinf(ang);
    float4 a = U0[q*2+0], b = U0[q*2+1];
    par[q] = fmaf(a.z, sv, a.x*c);
    pai[q] = fmaf(a.w, sv, a.y*c);
    pbr[q] = fmaf(b.z, sv, b.x*c);
    pbi[q] = fmaf(b.w, sv, b.y*c);
  }

  // lane-qubit product (qubits 4..9)
  float lr, li;
  {
    bool b0 = lane & 1;
    lr = b0 ? pbr[4] : par[4];
    li = b0 ? pbi[4] : pai[4];
  }
  #pragma unroll
  for (int j = 1; j < 6; ++j){
    int q = 4 + j;
    bool b = (lane >> j) & 1;
    float fr = b ? pbr[q] : par[q];
    float fi = b ? pbi[q] : pai[q];
    float t = lr*fr - li*fi;
    li = fmaf(lr, fi, li*fr);
    lr = t;
  }

  // register-qubit product tree (qubits 0..3)
  float re[16], im[16];
  re[0] = lr; im[0] = li;
  #pragma unroll
  for (int k = 0; k < 4; ++k){
    int w = 1 << k;
    #pragma unroll
    for (int r = 0; r < 8; ++r) if (r < w){
      float xr = re[r], xi = im[r];
      re[r|w] = xr*pbr[k] - xi*pbi[k];
      im[r|w] = fmaf(xr, pbi[k], xi*pbr[k]);
      re[r]   = xr*par[k] - xi*pai[k];
      im[r]   = fmaf(xr, pai[k], xi*par[k]);
    }
  }

  run_layer<1>(re, im, gc2, phase4, lane);
  run_layer<2>(re, im, gc2, phase4, lane);
  run_layer<3>(re, im, gc2, phase4, lane);
  run_layer<4>(re, im, gc2, phase4, lane);
  run_layer<5>(re, im, gc2, phase4, lane);

  // probabilities -> 16-point WHT over register bits
  float p[16];
  #pragma unroll
  for (int r = 0; r < 16; ++r) p[r] = fmaf(re[r], re[r], im[r]*im[r]);
  #pragma unroll
  for (int k = 0; k < 4; ++k){
    int w = 1 << k;
    #pragma unroll
    for (int r = 0; r < 16; ++r) if (!(r & w)){
      float a = p[r], b = p[r|w];
      p[r] = a + b; p[r|w] = a - b;
    }
  }
  // z_q partial = +/- p[R&15], sign from lane bits; fuse FC
  float o[4] = {0.f, 0.f, 0.f, 0.f};
  #pragma unroll
  for (int q = 0; q < NQ; ++q){
    constexpr int RALL[NQ] = {TAB.meas[0],TAB.meas[1],TAB.meas[2],TAB.meas[3],
                              TAB.meas[4],TAB.meas[5],TAB.meas[6],TAB.meas[7],
                              TAB.meas[8],TAB.meas[9]};
    int R = RALL[q];
    float tq = p[R & 15];
    unsigned sg = (unsigned)(__popc((R >> 4) & lane) << 31);
    tq = __uint_as_float(__float_as_uint(tq) ^ sg);
    #pragma unroll
    for (int j = 0; j < 4; ++j) o[j] = fmaf(tq, fcW[j*NQ + q], o[j]);
  }
  #pragma unroll
  for (int j = 0; j < 4; ++j){
    #pragma unroll
    for (int st = 1; st < 64; st <<= 1) o[j] += __shfl_xor(o[j], st, 64);
  }
  if (lane == 0){
    float4 out4 = make_float4(o[0]+fcB[0], o[1]+fcB[1], o[2]+fcB[2], o[3]+fcB[3]);
    *reinterpret_cast<float4*>(&outB[(size_t)s*4]) = out4;
  }
}

// ---- K3: deterministic BN stats (single block) ----
__global__ __launch_bounds__(1024) void k3_stats(const float* __restrict__ outB,
                                                 float* __restrict__ stats)
{
  int tid = threadIdx.x;
  float sum[4] = {0,0,0,0}, sq[4] = {0,0,0,0};
  for (int row = tid; row < B_SZ; row += 1024){
    float4 v = *reinterpret_cast<const float4*>(outB + (size_t)row*4);
    sum[0]+=v.x; sq[0]+=v.x*v.x;
    sum[1]+=v.y; sq[1]+=v.y*v.y;
    sum[2]+=v.z; sq[2]+=v.z*v.z;
    sum[3]+=v.w; sq[3]+=v.w*v.w;
  }
  #pragma unroll
  for (int k = 0; k < 4; ++k){
    #pragma unroll
    for (int st = 1; st < 64; st <<= 1){
      sum[k] += __shfl_xor(sum[k], st, 64);
      sq[k]  += __shfl_xor(sq[k],  st, 64);
    }
  }
  __shared__ float ls[16][8];
  int lane = tid & 63, w = tid >> 6;
  if (lane == 0){
    #pragma unroll
    for (int k = 0; k < 4; ++k){ ls[w][k] = sum[k]; ls[w][4+k] = sq[k]; }
  }
  __syncthreads();
  if (tid == 0){
    float fs[8];
    #pragma unroll
    for (int k = 0; k < 8; ++k){
      float a = 0.f;
      for (int w2 = 0; w2 < 16; ++w2) a += ls[w2][k];
      fs[k] = a;
    }
    #pragma unroll
    for (int k = 0; k < 4; ++k){
      float mean = fs[k] * (1.f/B_SZ);
      float var  = fs[4+k] * (1.f/B_SZ) - mean*mean;
      stats[k]   = mean;
      stats[4+k] = rsqrtf(var + 1e-5f);
    }
  }
}

// ---- K4: apply BN ----
__global__ __launch_bounds__(256) void k4_bn(const float* __restrict__ outB,
    const float* __restrict__ stats, const float* __restrict__ gamma,
    const float* __restrict__ beta, float* __restrict__ out)
{
  int idx = blockIdx.x * 256 + threadIdx.x;
  int c = idx & 3;
  float v = outB[idx];
  out[idx] = gamma[c] * (v - stats[c]) * stats[4+c] + beta[c];
}

extern "C" void kernel_launch(void* const* d_in, const int* in_sizes, int n_in,
                              void* d_out, int out_size, void* d_ws, size_t ws_size,
                              hipStream_t stream)
{
  const float* x     = (const float*)d_in[0];
  const float* encW  = (const float*)d_in[1];
  const float* encB  = (const float*)d_in[2];
  const float* wts   = (const float*)d_in[3];
  const float* fcW   = (const float*)d_in[4];
  const float* fcB   = (const float*)d_in[5];
  const float* gamma = (const float*)d_in[6];
  const float* beta  = (const float*)d_in[7];

  char* ws = (char*)d_ws;
  unsigned* gkey  = (unsigned*)ws;                      // 4 B
  float4*  U0     = (float4*)(ws + 256);                // 320 B
  float2*  gc2    = (float2*)(ws + 1024);               // 400 B
  float2*  phase  = (float2*)(ws + 4096);               // 32 KB
  float*   enc    = (float*)(ws + 4096 + 32768);
  float*   outB   = (float*)(ws + 4096 + 32768 + (size_t)B_SZ*NQ*4);
  float*   stats  = (float*)(ws + 4096 + 32768 + (size_t)B_SZ*NQ*4 + (size_t)B_SZ*4*4);

  hipLaunchKernelGGL(k_prep, dim3(16), dim3(256), 0, stream, wts, U0, gc2, phase, gkey);
  hipLaunchKernelGGL(k1_encode, dim3(B_SZ/256), dim3(256), 0, stream,
                     x, encW, encB, enc, gkey);
  hipLaunchKernelGGL(k2_qsim, dim3(B_SZ/4), dim3(256), 0, stream,
                     enc, gkey, U0, gc2, (const float4*)phase, fcW, fcB, outB);
  hipLaunchKernelGGL(k3_stats, dim3(1), dim3(1024), 0, stream, outB, stats);
  hipLaunchKernelGGL(k4_bn, dim3(B_SZ*4/256), dim3(256), 0, stream,
                     outB, stats, gamma, beta, (float*)d_out);
}